// Round 3
// baseline (113.835 us; speedup 1.0000x reference)
//
#include <hip/hip_runtime.h>
#include <math.h>

#define NB 10
#define NCLS 100

// 4 lanes per row, 16 rows per wave. Each lane loads 6 x float4 (64B
// contiguous per 4-lane group -> good TA coalescing) + 1 tail scalar.
// Exact first-occurrence argmax via 2-stage shuffle; softmax p of the true
// class; fp32 LDS partials -> double global atomics -> fp64 finalize.
__global__ __launch_bounds__(256) void ece_main(const float* __restrict__ outputs,
                                                const int* __restrict__ targets,
                                                double* __restrict__ gacc,
                                                int nrows) {
    __shared__ float s_cnt[NB], s_sp[NB], s_sc[NB];
    const int tid = threadIdx.x;
    if (tid < NB) { s_cnt[tid] = 0.f; s_sp[tid] = 0.f; s_sc[tid] = 0.f; }
    __syncthreads();

    const int lane = tid & 63;
    const int wid  = tid >> 6;
    const int q = lane & 3;        // quarter within row
    const int g = lane >> 2;       // row group 0..15
    const int gwave  = blockIdx.x * 4 + wid;
    const int nwaves = gridDim.x * 4;
    const int ntiles = (nrows + 15) >> 4;

    const float NEG_INF = -__builtin_inff();

    for (int tile = gwave; tile < ntiles; tile += nwaves) {
        const int row = tile * 16 + g;
        const bool active = row < nrows;

        float4 v[6];
        float tail;
        int t;
        if (active) {
            const float* __restrict__ R = outputs + (size_t)row * NCLS;
            #pragma unroll
            for (int k = 0; k < 6; ++k)
                v[k] = *reinterpret_cast<const float4*>(R + q * 4 + k * 16);
            tail = R[96 + q];
            t = targets[row];
        } else {
            #pragma unroll
            for (int k = 0; k < 6; ++k) v[k].x = v[k].y = v[k].z = v[k].w = NEG_INF;
            tail = NEG_INF;
            t = -1;
        }

        // local (max, argcol), first occurrence = lowest col wins on ties.
        // lane's cols ascend: k*16 + q*4 + e, then tail col 96+q.
        float m = v[0].x;
        int   c = q * 4;
        #pragma unroll
        for (int k = 0; k < 6; ++k) {
            const int base = k * 16 + q * 4;
            if (k > 0 && v[k].x > m) { m = v[k].x; c = base; }
            if (v[k].y > m) { m = v[k].y; c = base + 1; }
            if (v[k].z > m) { m = v[k].z; c = base + 2; }
            if (v[k].w > m) { m = v[k].w; c = base + 3; }
        }
        if (tail > m) { m = tail; c = 96 + q; }

        // group reduce (max, argcol) over the 4 lanes: xor 1, xor 2
        #pragma unroll
        for (int off = 1; off <= 2; off <<= 1) {
            const float om = __shfl_xor(m, off);
            const int   oc = __shfl_xor(c, off);
            if (om > m || (om == m && oc < c)) { m = om; c = oc; }
        }

        // sum of exp(x - m); pick out the target element on the way
        float s = 0.f, te = 0.f;
        #pragma unroll
        for (int k = 0; k < 6; ++k) {
            const int base = k * 16 + q * 4;
            const float e0 = __expf(v[k].x - m);
            const float e1 = __expf(v[k].y - m);
            const float e2 = __expf(v[k].z - m);
            const float e3 = __expf(v[k].w - m);
            s += (e0 + e1) + (e2 + e3);
            if (base     == t) te = e0;
            if (base + 1 == t) te = e1;
            if (base + 2 == t) te = e2;
            if (base + 3 == t) te = e3;
        }
        {
            const float et = __expf(tail - m);
            s += et;
            if (96 + q == t) te = et;
        }
        #pragma unroll
        for (int off = 1; off <= 2; off <<= 1) {
            s  += __shfl_xor(s, off);
            te += __shfl_xor(te, off);
        }

        if (q == 0 && active) {
            const float p = te / s;                 // in (0, 1]
            const float corr = (c == t) ? 1.0f : 0.0f;
            // bin = (#boundaries strictly < p) - 1 ; p==0 -> excluded
            const float b[NB + 1] = {0.0f, 0.1f, 0.2f, 0.3f, 0.4f, 0.5f,
                                     0.6f, 0.7f, 0.8f, 0.9f, 1.0f};
            int j = 0;
            #pragma unroll
            for (int k = 0; k <= NB; ++k) j += (b[k] < p) ? 1 : 0;
            int bin = j - 1;
            if (bin >= 0) {
                if (bin > NB - 1) bin = NB - 1;
                atomicAdd(&s_cnt[bin], 1.0f);
                atomicAdd(&s_sp[bin], p);
                atomicAdd(&s_sc[bin], corr);
            }
        }
    }

    __syncthreads();
    if (tid < NB) {
        atomicAdd(&gacc[tid],          (double)s_cnt[tid]);
        atomicAdd(&gacc[NB + tid],     (double)s_sp[tid]);
        atomicAdd(&gacc[2 * NB + tid], (double)s_sc[tid]);
    }
}

__global__ void ece_final(const double* __restrict__ gacc, float* __restrict__ out) {
    if (threadIdx.x == 0 && blockIdx.x == 0) {
        double ece = 0.0, total = 0.0;
        for (int i = 0; i < NB; ++i) {
            const double c = gacc[i];
            if (c > 0.0) {
                const double ap = gacc[NB + i] / c;
                const double ac = gacc[2 * NB + i] / c;
                ece += c * fabs(ap - ac);
                total += c;
            }
        }
        out[0] = (total > 0.0) ? (float)(ece / total) : 0.0f;
    }
}

extern "C" void kernel_launch(void* const* d_in, const int* in_sizes, int n_in,
                              void* d_out, int out_size, void* d_ws, size_t ws_size,
                              hipStream_t stream) {
    const float* outputs = (const float*)d_in[0];
    const int*   targets = (const int*)d_in[1];
    float* out   = (float*)d_out;
    double* gacc = (double*)d_ws;

    const int nrows = in_sizes[1];  // 1,000,000

    hipMemsetAsync(gacc, 0, 3 * NB * sizeof(double), stream);

    const int blocks = 2048;  // 8192 waves, ~7.6 tiles of 16 rows each
    ece_main<<<blocks, 256, 0, stream>>>(outputs, targets, gacc, nrows);
    ece_final<<<1, 64, 0, stream>>>(gacc, out);
}